// Round 7
// baseline (93.826 us; speedup 1.0000x reference)
//
#include <hip/hip_runtime.h>
#include <math.h>

// BayesPredictor: inputs [B,D] f32, alphas [B] f32, data [N,D] f32
#define BB 32
#define DD 128
#define NN 32768

#define NB 512              // k1 blocks
#define RPB 64              // data rows per block
#define WS_STRIDE 136       // f32 per (b, block) partial: m, s, pad, pad, acc[128], pad[4]
#define NP NB               // partials per b
#define WSB_OFF ((size_t)BB * NP * WS_STRIDE)   // second ws region (A/B timing probe)

typedef __attribute__((ext_vector_type(8))) short bf16x8;
typedef __attribute__((ext_vector_type(4))) float f32x4;

// ---- LDS arena (bytes). Swizzle: 16B-granule XOR ((row&7)<<4) on every tile.
#define O_RH   0            // rows hi  bf16 [64][128] pitch 256
#define O_RL   16384        // rows lo  bf16 [64][128] pitch 256
#define O_INH  32768        // inputs hi bf16 [32][128] pitch 256
#define O_INL  40960        // inputs lo
#define O_RT   49152        // rows^T hi bf16 [128][64] pitch 128
#define O_D1   65536        // GEMM1 k-partials: [ni(2)][mt(4)][b(16)] pitch 80, f32x4 per g
#define O_NRM  75776        // 64 row norms f32
#define O_PT   O_INH        // P^T bf16 [32 b][64 r] pitch 128 (overlays inh after GEMM1)
#define O_X0   O_RH         // x0 f32 [32 b][128 d] pitch 512 (overlays Rh after GEMM1)
#define ARENA  76032

__device__ __forceinline__ unsigned bf16_rne(float x) {
    unsigned u = __builtin_bit_cast(unsigned, x);
    return (u + 0x7FFFu + ((u >> 16) & 1u)) >> 16;
}
__device__ __forceinline__ float bf16f(unsigned h) {
    return __builtin_bit_cast(float, h << 16);
}
__device__ __forceinline__ unsigned pk2(float a, float b) {
    return bf16_rne(a) | (bf16_rne(b) << 16);
}

// ---------------- kernel 1: per-block (64 rows) flash step via split-bf16 MFMA ----------------
__global__ __launch_bounds__(256) void bayes_k1(
    const float* __restrict__ inputs, const float* __restrict__ alphas,
    const float* __restrict__ data, float* __restrict__ ws)
{
    __shared__ __align__(16) char arena[ARENA];

    const int tid  = threadIdx.x;
    const int lane = tid & 63;
    const int wv   = tid >> 6;       // 0..3
    const int ln   = lane & 15;
    const int g    = lane >> 4;      // 0..3
    const int bid  = blockIdx.x;

    // ---- stage A: rows -> Rh/Rl (hi/lo split) + f32 norms. t: r=t>>2, 32-float chunk c4.
    {
        const int r = tid >> 2, c4 = tid & 3;
        const float4* gp = (const float4*)(data + ((size_t)bid * RPB + r) * DD + c4 * 32);
        float v[32];
        #pragma unroll
        for (int i = 0; i < 8; ++i) {
            const float4 t4 = gp[i];
            v[4*i+0] = t4.x; v[4*i+1] = t4.y; v[4*i+2] = t4.z; v[4*i+3] = t4.w;
        }
        float nn = 0.0f;
        #pragma unroll
        for (int i = 0; i < 32; ++i) nn = fmaf(v[i], v[i], nn);
        nn += __shfl_xor(nn, 1);
        nn += __shfl_xor(nn, 2);
        if (c4 == 0) *(float*)(arena + O_NRM + r * 4) = nn;

        const int swz = (r & 7) << 4;
        #pragma unroll
        for (int u = 0; u < 4; ++u) {       // 4 granules of 8 bf16
            unsigned hw[4], lw[4];
            #pragma unroll
            for (int j = 0; j < 4; ++j) {
                const float a = v[u*8 + 2*j], b = v[u*8 + 2*j + 1];
                const unsigned ah = bf16_rne(a), bh = bf16_rne(b);
                hw[j] = ah | (bh << 16);
                lw[j] = pk2(a - bf16f(ah), b - bf16f(bh));
            }
            const int go = (c4 * 64 + u * 16) ^ swz;
            *(uint4*)(arena + O_RH + r * 256 + go) = make_uint4(hw[0], hw[1], hw[2], hw[3]);
            *(uint4*)(arena + O_RL + r * 256 + go) = make_uint4(lw[0], lw[1], lw[2], lw[3]);
        }
    }

    // ---- stage A2: inputs -> inh/inl. t: b=t>>3, 16-float chunk c8.
    {
        const int b = tid >> 3, c8 = tid & 7;
        const float4* gp = (const float4*)(inputs + b * DD + c8 * 16);
        float v[16];
        #pragma unroll
        for (int i = 0; i < 4; ++i) {
            const float4 t4 = gp[i];
            v[4*i+0] = t4.x; v[4*i+1] = t4.y; v[4*i+2] = t4.z; v[4*i+3] = t4.w;
        }
        const int swz = (b & 7) << 4;
        #pragma unroll
        for (int u = 0; u < 2; ++u) {
            unsigned hw[4], lw[4];
            #pragma unroll
            for (int j = 0; j < 4; ++j) {
                const float a = v[u*8 + 2*j], bb = v[u*8 + 2*j + 1];
                const unsigned ah = bf16_rne(a), bh = bf16_rne(bb);
                hw[j] = ah | (bh << 16);
                lw[j] = pk2(a - bf16f(ah), bb - bf16f(bh));
            }
            const int go = (c8 * 32 + u * 16) ^ swz;
            *(uint4*)(arena + O_INH + b * 256 + go) = make_uint4(hw[0], hw[1], hw[2], hw[3]);
            *(uint4*)(arena + O_INL + b * 256 + go) = make_uint4(lw[0], lw[1], lw[2], lw[3]);
        }
    }

    // ---- stage B: transposed re-read (L2-hot) -> RT hi. t: d=t>>1, r-half rh.
    {
        const int d = tid >> 1, rh = tid & 1;
        const float* gc = data + ((size_t)bid * RPB + rh * 32) * DD + d;
        const int swz = (d & 7) << 4;
        #pragma unroll
        for (int u = 0; u < 4; ++u) {       // granule u: local rows u*8..u*8+7
            unsigned w[4];
            #pragma unroll
            for (int j = 0; j < 4; ++j)
                w[j] = pk2(gc[(u*8 + 2*j) * DD], gc[(u*8 + 2*j + 1) * DD]);
            *(uint4*)(arena + O_RT + d * 128 + ((rh * 64 + u * 16) ^ swz)) =
                make_uint4(w[0], w[1], w[2], w[3]);
        }
    }
    __syncthreads();

    // ---- GEMM-1: L[r,b] = rows · in^T, split-bf16 3-term, K-split across wave pairs
    const int ni = wv & 1;   // b-half
    const int kh = wv >> 1;  // k-half
    f32x4 acc1[4];
    #pragma unroll
    for (int mt = 0; mt < 4; ++mt)
        #pragma unroll
        for (int i = 0; i < 4; ++i) acc1[mt][i] = 0.0f;

    #pragma unroll
    for (int ks = 0; ks < 2; ++ks) {
        const int kbyte = kh * 128 + ks * 64 + g * 16;
        const int n = ni * 16 + ln;
        const bf16x8 Bh = *(const bf16x8*)(arena + O_INH + n * 256 + (kbyte ^ ((n & 7) << 4)));
        const bf16x8 Bl = *(const bf16x8*)(arena + O_INL + n * 256 + (kbyte ^ ((n & 7) << 4)));
        #pragma unroll
        for (int mt = 0; mt < 4; ++mt) {
            const int r = mt * 16 + ln;
            const bf16x8 Ah = *(const bf16x8*)(arena + O_RH + r * 256 + (kbyte ^ ((r & 7) << 4)));
            const bf16x8 Al = *(const bf16x8*)(arena + O_RL + r * 256 + (kbyte ^ ((r & 7) << 4)));
            acc1[mt] = __builtin_amdgcn_mfma_f32_16x16x32_bf16(Ah, Bh, acc1[mt], 0, 0, 0);
            acc1[mt] = __builtin_amdgcn_mfma_f32_16x16x32_bf16(Al, Bh, acc1[mt], 0, 0, 0);
            acc1[mt] = __builtin_amdgcn_mfma_f32_16x16x32_bf16(Ah, Bl, acc1[mt], 0, 0, 0);
        }
    }
    if (kh == 1) {
        #pragma unroll
        for (int mt = 0; mt < 4; ++mt)
            *(f32x4*)(arena + O_D1 + ((ni * 4 + mt) * 16 + ln) * 80 + g * 16) = acc1[mt];
    }
    __syncthreads();

    // ---- softmax (waves 0,1): merge k-halves, logits, max/exp/sum, P^T bf16, write m,s
    if (kh == 0) {
        const int b = ni * 16 + ln;
        #pragma unroll
        for (int mt = 0; mt < 4; ++mt) {
            const f32x4 o = *(const f32x4*)(arena + O_D1 + ((ni * 4 + mt) * 16 + ln) * 80 + g * 16);
            #pragma unroll
            for (int i = 0; i < 4; ++i) acc1[mt][i] += o[i];
        }
        const float alpha = alphas[b];
        const float var = 1.0f - alpha;
        const float c1 = sqrtf(alpha) / var;
        const float c2 = 0.5f * alpha / var;

        float lg[4][4];
        float mx = -1e30f;
        #pragma unroll
        for (int mt = 0; mt < 4; ++mt) {
            const f32x4 nr4 = *(const f32x4*)(arena + O_NRM + (mt * 16 + g * 4) * 4);
            #pragma unroll
            for (int i = 0; i < 4; ++i) {
                lg[mt][i] = fmaf(c1, acc1[mt][i], -c2 * nr4[i]);
                mx = fmaxf(mx, lg[mt][i]);
            }
        }
        mx = fmaxf(mx, __shfl_xor(mx, 16));
        mx = fmaxf(mx, __shfl_xor(mx, 32));

        float ss = 0.0f;
        const int swz = (b & 7) << 4;
        #pragma unroll
        for (int mt = 0; mt < 4; ++mt) {
            float e0 = __expf(lg[mt][0] - mx), e1 = __expf(lg[mt][1] - mx);
            float e2 = __expf(lg[mt][2] - mx), e3 = __expf(lg[mt][3] - mx);
            ss += (e0 + e1) + (e2 + e3);
            *(uint2*)(arena + O_PT + b * 128 + ((mt * 32 + g * 8) ^ swz)) =
                make_uint2(pk2(e0, e1), pk2(e2, e3));
        }
        ss += __shfl_xor(ss, 16);
        ss += __shfl_xor(ss, 32);
        if (g == 0) {
            float* wsp = ws + ((size_t)b * NB + bid) * WS_STRIDE;
            wsp[0] = mx; wsp[1] = ss;
        }
    }
    __syncthreads();

    // ---- PV: x0^T[d,b] = rows^T(hi) · P  (K = 64 rows, d split across 4 waves)
    {
        f32x4 acc2[2][2];
        #pragma unroll
        for (int a = 0; a < 2; ++a)
            #pragma unroll
            for (int c = 0; c < 2; ++c)
                #pragma unroll
                for (int i = 0; i < 4; ++i) acc2[a][c][i] = 0.0f;

        #pragma unroll
        for (int ks = 0; ks < 2; ++ks) {
            bf16x8 Bp[2];
            #pragma unroll
            for (int nt = 0; nt < 2; ++nt) {
                const int b2 = nt * 16 + ln;
                Bp[nt] = *(const bf16x8*)(arena + O_PT + b2 * 128 +
                                          ((ks * 64 + g * 16) ^ ((b2 & 7) << 4)));
            }
            #pragma unroll
            for (int mt2 = 0; mt2 < 2; ++mt2) {
                const int d = wv * 32 + mt2 * 16 + ln;
                const bf16x8 Ar = *(const bf16x8*)(arena + O_RT + d * 128 +
                                                   ((ks * 64 + g * 16) ^ ((d & 7) << 4)));
                #pragma unroll
                for (int nt = 0; nt < 2; ++nt)
                    acc2[mt2][nt] = __builtin_amdgcn_mfma_f32_16x16x32_bf16(Ar, Bp[nt], acc2[mt2][nt], 0, 0, 0);
            }
        }
        // x0 bounce -> LDS [b][d] f32 (overlays Rh; Rh dead since GEMM-1)
        #pragma unroll
        for (int mt2 = 0; mt2 < 2; ++mt2)
            #pragma unroll
            for (int nt = 0; nt < 2; ++nt) {
                const int b = nt * 16 + ln;
                const int d0 = wv * 32 + mt2 * 16 + g * 4;
                *(f32x4*)(arena + O_X0 + b * 512 + ((d0 * 4) ^ ((b & 7) << 4))) = acc2[mt2][nt];
            }
    }
    __syncthreads();

    // ---- coalesced partial write: ws[b][bid][4..132] = x0 row
    {
        const int b = tid >> 3, c8 = tid & 7;
        const int swz = (b & 7) << 4;
        float* dst = ws + ((size_t)b * NB + bid) * WS_STRIDE + 4 + c8 * 16;
        #pragma unroll
        for (int u = 0; u < 4; ++u) {
            const f32x4 v = *(const f32x4*)(arena + O_X0 + b * 512 + ((c8 * 64 + u * 16) ^ swz));
            *(f32x4*)(dst + u * 4) = v;
        }
    }
}

// ---------------- kernel 2: cross-block softmax combine + output (b-major ws) ----------------
__global__ __launch_bounds__(256) void bayes_k2(
    const float* __restrict__ inputs, const float* __restrict__ alphas,
    const float* __restrict__ ws, float* __restrict__ out)
{
    const int b   = blockIdx.x >> 2;   // 0..31
    const int dq  = blockIdx.x & 3;    // d-quarter
    const int tid = threadIdx.x;

    __shared__ float e_s[NP];
    __shared__ float red_s[16];
    __shared__ float part[8][32];

    const float* base_b = ws + (size_t)b * NP * WS_STRIDE;

    float mi[2], si[2];
    #pragma unroll
    for (int q = 0; q < 2; ++q) {
        const int i = tid + q * 256;
        mi[q] = base_b[(size_t)i * WS_STRIDE];
        si[q] = base_b[(size_t)i * WS_STRIDE + 1];
    }

    float mm = fmaxf(mi[0], mi[1]);
    #pragma unroll
    for (int off = 1; off <= 32; off <<= 1) mm = fmaxf(mm, __shfl_xor(mm, off));
    if ((tid & 63) == 0) red_s[tid >> 6] = mm;
    __syncthreads();
    const float M = fmaxf(fmaxf(red_s[0], red_s[1]), fmaxf(red_s[2], red_s[3]));

    float ss = 0.0f;
    #pragma unroll
    for (int q = 0; q < 2; ++q) {
        const float ei = __expf(mi[q] - M);
        e_s[tid + q * 256] = ei;
        ss = fmaf(si[q], ei, ss);
    }
    #pragma unroll
    for (int off = 1; off <= 32; off <<= 1) ss += __shfl_xor(ss, off);
    if ((tid & 63) == 0) red_s[8 + (tid >> 6)] = ss;
    __syncthreads();
    const float S = (red_s[8] + red_s[9]) + (red_s[10] + red_s[11]);

    // x0 slice: 32 d-values, 8-way split over 512 partials (64 each); contiguous region per b
    const int dd = tid & 31, ii = tid >> 5;
    const int d  = dq * 32 + dd;
    float x = 0.0f;
    #pragma unroll 8
    for (int k = 0; k < 64; ++k) {
        const int i = ii + k * 8;
        x = fmaf(e_s[i], base_b[(size_t)i * WS_STRIDE + 4 + d], x);
    }
    part[ii][dd] = x;
    __syncthreads();

    if (tid < 32) {
        float x0 = 0.0f;
        #pragma unroll
        for (int p = 0; p < 8; ++p) x0 += part[p][tid];
        x0 /= S;
        const float alpha = alphas[b];
        const float sa  = sqrtf(alpha);
        const float var = 1.0f - alpha;
        const int dout  = dq * 32 + tid;
        out[b * DD + dout] = (inputs[b * DD + dout] - sa * x0) / sqrtf(var);
    }
}

extern "C" void kernel_launch(void* const* d_in, const int* in_sizes, int n_in,
                              void* d_out, int out_size, void* d_ws, size_t ws_size,
                              hipStream_t stream)
{
    const float* inputs = (const float*)d_in[0];   // [B,D]
    const float* alphas = (const float*)d_in[1];   // [B]
    const float* data   = (const float*)d_in[2];   // [N,D]
    float* out = (float*)d_out;
    float* ws  = (float*)d_ws;                     // region A + region B (timing probe)

    // A/B timing probe: k1 launched twice. k1a -> wsA feeds k2 (correctness path).
    // k1b -> wsB is identical work whose output is never read; its runtime shows up
    // 1:1 in dur_us, giving k1's isolated duration as dur(round7) - dur(round6).
    bayes_k1<<<NB, 256, 0, stream>>>(inputs, alphas, data, ws);
    bayes_k1<<<NB, 256, 0, stream>>>(inputs, alphas, data, ws + WSB_OFF);
    bayes_k2<<<BB * 4, 256, 0, stream>>>(inputs, alphas, ws, out);
}

// Round 8
// 92.487 us; speedup vs baseline: 1.0145x; 1.0145x over previous
//
#include <hip/hip_runtime.h>
#include <math.h>

// BayesPredictor: inputs [B,D] f32, alphas [B] f32, data [N,D] f32
#define BB 32
#define DD 128
#define NN 32768

#define NB 1024             // k1 blocks
#define RPB 32              // data rows per block
#define NP NB               // partials per b
// ws map: x0 partials [b][bid][128] f32 contiguous, then packed ms [b][bid] float2
#define WS_MS_OFF ((size_t)BB * NB * DD)

typedef __attribute__((ext_vector_type(8))) short bf16x8;
typedef __attribute__((ext_vector_type(4))) float f32x4;

// ---- LDS arena (bytes). 16B-granule XOR swizzle per tile.
#define O_RH   0            // rows hi  bf16 [32][128] pitch 256, swz (r&7)<<4
#define O_RL   8192         // rows lo
#define O_INH  16384        // inputs hi bf16 [32][128] pitch 256, swz (b&7)<<4
#define O_INL  24576        // inputs lo
#define O_RT   32768        // rows^T hi bf16 [128][32] pitch 64, swz (d&3)<<4
#define O_NRM  40960        // 32 row norms f32 (128 B)
#define O_LQ   41088        // L quadrants f32 [32 r][32 b] pitch 128 (4 KB)
#define ARENA  45184        // -> 3 blocks/CU
#define O_PT   O_INH        // P^T bf16 [32 b][32 r] pitch 64, swz (b&3)<<4 (post-GEMM1)
#define O_X0   O_RH         // x0 f32 [32 b][128 d] pitch 512, swz (b&7)<<4 (post-GEMM1)

__device__ __forceinline__ unsigned bf16_rne(float x) {
    unsigned u = __builtin_bit_cast(unsigned, x);
    return (u + 0x7FFFu + ((u >> 16) & 1u)) >> 16;
}
__device__ __forceinline__ float bf16f(unsigned h) {
    return __builtin_bit_cast(float, h << 16);
}
__device__ __forceinline__ unsigned pk2(float a, float b) {
    return bf16_rne(a) | (bf16_rne(b) << 16);
}

// ---------------- kernel 1: per-block (32 rows) flash step via split-bf16 MFMA ----------------
// 4-barrier schedule: stage -> B1 -> GEMM1(1 tile/wave, full K) -> B2 -> softmax -> B3 -> PV -> B4 -> write
__global__ __launch_bounds__(256) void bayes_k1(
    const float* __restrict__ inputs, const float* __restrict__ alphas,
    const float* __restrict__ data, float* __restrict__ ws)
{
    __shared__ __align__(16) char arena[ARENA];

    const int tid  = threadIdx.x;
    const int lane = tid & 63;
    const int wv   = tid >> 6;       // 0..3
    const int ln   = lane & 15;
    const int g    = lane >> 4;      // 0..3
    const int bid  = blockIdx.x;

    // ---- stage A: rows -> Rh/Rl + norms. thread: r = tid>>3, 16-float chunk c8.
    {
        const int r = tid >> 3, c8 = tid & 7;
        const float4* gp = (const float4*)(data + ((size_t)bid * RPB + r) * DD + c8 * 16);
        float v[16];
        #pragma unroll
        for (int i = 0; i < 4; ++i) {
            const float4 t4 = gp[i];
            v[4*i+0] = t4.x; v[4*i+1] = t4.y; v[4*i+2] = t4.z; v[4*i+3] = t4.w;
        }
        float nn = 0.0f;
        #pragma unroll
        for (int i = 0; i < 16; ++i) nn = fmaf(v[i], v[i], nn);
        nn += __shfl_xor(nn, 1);
        nn += __shfl_xor(nn, 2);
        nn += __shfl_xor(nn, 4);
        if (c8 == 0) *(float*)(arena + O_NRM + r * 4) = nn;

        const int swz = (r & 7) << 4;
        #pragma unroll
        for (int u = 0; u < 2; ++u) {
            unsigned hw[4], lw[4];
            #pragma unroll
            for (int j = 0; j < 4; ++j) {
                const float a = v[u*8 + 2*j], b = v[u*8 + 2*j + 1];
                const unsigned ah = bf16_rne(a), bh = bf16_rne(b);
                hw[j] = ah | (bh << 16);
                lw[j] = pk2(a - bf16f(ah), b - bf16f(bh));
            }
            const int go = (c8 * 32 + u * 16) ^ swz;
            *(uint4*)(arena + O_RH + r * 256 + go) = make_uint4(hw[0], hw[1], hw[2], hw[3]);
            *(uint4*)(arena + O_RL + r * 256 + go) = make_uint4(lw[0], lw[1], lw[2], lw[3]);
        }
    }

    // ---- stage A2: inputs -> inh/inl. thread: b = tid>>3, chunk c8.
    {
        const int b = tid >> 3, c8 = tid & 7;
        const float4* gp = (const float4*)(inputs + b * DD + c8 * 16);
        float v[16];
        #pragma unroll
        for (int i = 0; i < 4; ++i) {
            const float4 t4 = gp[i];
            v[4*i+0] = t4.x; v[4*i+1] = t4.y; v[4*i+2] = t4.z; v[4*i+3] = t4.w;
        }
        const int swz = (b & 7) << 4;
        #pragma unroll
        for (int u = 0; u < 2; ++u) {
            unsigned hw[4], lw[4];
            #pragma unroll
            for (int j = 0; j < 4; ++j) {
                const float a = v[u*8 + 2*j], bb = v[u*8 + 2*j + 1];
                const unsigned ah = bf16_rne(a), bh = bf16_rne(bb);
                hw[j] = ah | (bh << 16);
                lw[j] = pk2(a - bf16f(ah), bb - bf16f(bh));
            }
            const int go = (c8 * 32 + u * 16) ^ swz;
            *(uint4*)(arena + O_INH + b * 256 + go) = make_uint4(hw[0], hw[1], hw[2], hw[3]);
            *(uint4*)(arena + O_INL + b * 256 + go) = make_uint4(lw[0], lw[1], lw[2], lw[3]);
        }
    }

    // ---- stage B: transposed re-read (L2-hot) -> RT hi. thread: d = tid>>1, row-half rh.
    {
        const int d = tid >> 1, rh = tid & 1;
        const float* gc = data + ((size_t)bid * RPB + rh * 16) * DD + d;
        const int swz = (d & 3) << 4;
        #pragma unroll
        for (int u = 0; u < 2; ++u) {       // granule u: local rows rh*16 + u*8 .. +7
            unsigned w[4];
            #pragma unroll
            for (int j = 0; j < 4; ++j)
                w[j] = pk2(gc[(u*8 + 2*j) * DD], gc[(u*8 + 2*j + 1) * DD]);
            *(uint4*)(arena + O_RT + d * 64 + ((rh * 32 + u * 16) ^ swz)) =
                make_uint4(w[0], w[1], w[2], w[3]);
        }
    }
    __syncthreads();   // B1

    // ---- GEMM-1: L[r,b] = rows · in^T; wave (mt,nt) owns one 16x16 tile, full K=128
    {
        const int mt = wv >> 1, nt = wv & 1;
        const int r  = mt * 16 + ln;
        const int b2 = nt * 16 + ln;
        f32x4 acc1;
        #pragma unroll
        for (int i = 0; i < 4; ++i) acc1[i] = 0.0f;

        #pragma unroll
        for (int ks = 0; ks < 4; ++ks) {
            const int kbyte = ks * 64 + g * 16;
            const bf16x8 Bh = *(const bf16x8*)(arena + O_INH + b2 * 256 + (kbyte ^ ((b2 & 7) << 4)));
            const bf16x8 Bl = *(const bf16x8*)(arena + O_INL + b2 * 256 + (kbyte ^ ((b2 & 7) << 4)));
            const bf16x8 Ah = *(const bf16x8*)(arena + O_RH  + r  * 256 + (kbyte ^ ((r  & 7) << 4)));
            const bf16x8 Al = *(const bf16x8*)(arena + O_RL  + r  * 256 + (kbyte ^ ((r  & 7) << 4)));
            acc1 = __builtin_amdgcn_mfma_f32_16x16x32_bf16(Ah, Bh, acc1, 0, 0, 0);
            acc1 = __builtin_amdgcn_mfma_f32_16x16x32_bf16(Al, Bh, acc1, 0, 0, 0);
            acc1 = __builtin_amdgcn_mfma_f32_16x16x32_bf16(Ah, Bl, acc1, 0, 0, 0);
        }
        // publish L quadrant: row = mt*16 + g*4 + i, col = b2
        #pragma unroll
        for (int i = 0; i < 4; ++i)
            *(float*)(arena + O_LQ + (((mt * 16 + g * 4 + i) * 32) + nt * 16 + ln) * 4) = acc1[i];
    }
    __syncthreads();   // B2

    // ---- softmax (waves 0,1): full 32-row column per b, write P^T bf16 + packed m,s
    if (wv < 2) {
        const int b = wv * 16 + ln;
        const float alpha = alphas[b];
        const float var = 1.0f - alpha;
        const float c1 = sqrtf(alpha) / var;
        const float c2 = 0.5f * alpha / var;

        float lg[8];
        float mx = -1e30f;
        #pragma unroll
        for (int j = 0; j < 8; ++j) {
            const int r = g * 8 + j;
            const float L  = *(const float*)(arena + O_LQ + (r * 32 + b) * 4);
            const float nr = *(const float*)(arena + O_NRM + r * 4);
            lg[j] = fmaf(c1, L, -c2 * nr);
            mx = fmaxf(mx, lg[j]);
        }
        mx = fmaxf(mx, __shfl_xor(mx, 16));
        mx = fmaxf(mx, __shfl_xor(mx, 32));

        float e[8];
        float ss = 0.0f;
        #pragma unroll
        for (int j = 0; j < 8; ++j) { e[j] = __expf(lg[j] - mx); ss += e[j]; }
        ss += __shfl_xor(ss, 16);
        ss += __shfl_xor(ss, 32);

        *(uint4*)(arena + O_PT + b * 64 + ((g * 16) ^ ((b & 3) << 4))) =
            make_uint4(pk2(e[0], e[1]), pk2(e[2], e[3]), pk2(e[4], e[5]), pk2(e[6], e[7]));
        if (g == 0)
            *(float2*)(ws + WS_MS_OFF + ((size_t)b * NB + bid) * 2) = make_float2(mx, ss);
    }
    __syncthreads();   // B3

    // ---- PV: D[d,b] = rows^T(hi) · P ; K=32 -> one MFMA per 16x16 tile; wave owns 2 d-tiles
    {
        f32x4 acc2[2][2];
        #pragma unroll
        for (int a = 0; a < 2; ++a)
            #pragma unroll
            for (int c = 0; c < 2; ++c)
                #pragma unroll
                for (int i = 0; i < 4; ++i) acc2[a][c][i] = 0.0f;

        bf16x8 Bp[2];
        #pragma unroll
        for (int nt = 0; nt < 2; ++nt) {
            const int b2 = nt * 16 + ln;
            Bp[nt] = *(const bf16x8*)(arena + O_PT + b2 * 64 + ((g * 16) ^ ((b2 & 3) << 4)));
        }
        #pragma unroll
        for (int a = 0; a < 2; ++a) {
            const int d = (wv * 2 + a) * 16 + ln;
            const bf16x8 Ar = *(const bf16x8*)(arena + O_RT + d * 64 + ((g * 16) ^ ((d & 3) << 4)));
            #pragma unroll
            for (int nt = 0; nt < 2; ++nt)
                acc2[a][nt] = __builtin_amdgcn_mfma_f32_16x16x32_bf16(Ar, Bp[nt], acc2[a][nt], 0, 0, 0);
        }
        // bounce x0 -> LDS [b][d] f32 (overlays Rh/Rl, dead since GEMM1)
        #pragma unroll
        for (int a = 0; a < 2; ++a)
            #pragma unroll
            for (int nt = 0; nt < 2; ++nt) {
                const int b  = nt * 16 + ln;
                const int d0 = (wv * 2 + a) * 16 + g * 4;
                *(f32x4*)(arena + O_X0 + b * 512 + ((d0 * 4) ^ ((b & 7) << 4))) = acc2[a][nt];
            }
    }
    __syncthreads();   // B4

    // ---- coalesced partial write: ws[b][bid][0..127] (contiguous)
    {
        const int b = tid >> 3, c8 = tid & 7;
        const int swz = (b & 7) << 4;
        float* dst = ws + ((size_t)b * NB + bid) * DD + c8 * 16;
        #pragma unroll
        for (int u = 0; u < 4; ++u) {
            const f32x4 v = *(const f32x4*)(arena + O_X0 + b * 512 + ((c8 * 64 + u * 16) ^ swz));
            *(f32x4*)(dst + u * 4) = v;
        }
    }
}

// ---------------- kernel 2: cross-block softmax combine + output ----------------
__global__ __launch_bounds__(256) void bayes_k2(
    const float* __restrict__ inputs, const float* __restrict__ alphas,
    const float* __restrict__ ws, float* __restrict__ out)
{
    const int b   = blockIdx.x >> 2;   // 0..31
    const int dq  = blockIdx.x & 3;    // d-quarter
    const int tid = threadIdx.x;

    __shared__ float e_s[NP];
    __shared__ float red_s[16];
    __shared__ float part[8][32];

    // packed m,s: 1024 float2, contiguous per b
    const float* msb = ws + WS_MS_OFF + (size_t)b * NP * 2;
    float mi[4], si[4];
    #pragma unroll
    for (int q = 0; q < 4; ++q) {
        const float2 v = *(const float2*)(msb + (tid + q * 256) * 2);
        mi[q] = v.x; si[q] = v.y;
    }

    float mm = fmaxf(fmaxf(mi[0], mi[1]), fmaxf(mi[2], mi[3]));
    #pragma unroll
    for (int off = 1; off <= 32; off <<= 1) mm = fmaxf(mm, __shfl_xor(mm, off));
    if ((tid & 63) == 0) red_s[tid >> 6] = mm;
    __syncthreads();
    const float M = fmaxf(fmaxf(red_s[0], red_s[1]), fmaxf(red_s[2], red_s[3]));

    float ss = 0.0f;
    #pragma unroll
    for (int q = 0; q < 4; ++q) {
        const float ei = __expf(mi[q] - M);
        e_s[tid + q * 256] = ei;
        ss = fmaf(si[q], ei, ss);
    }
    #pragma unroll
    for (int off = 1; off <= 32; off <<= 1) ss += __shfl_xor(ss, off);
    if ((tid & 63) == 0) red_s[8 + (tid >> 6)] = ss;
    __syncthreads();
    const float S = (red_s[8] + red_s[9]) + (red_s[10] + red_s[11]);

    // gather: 32 d-values, 8-way split over 1024 partials (128 each), coalesced rows
    const int dd = tid & 31, ii = tid >> 5;
    const int d  = dq * 32 + dd;
    const float* xb = ws + (size_t)b * NP * DD + d;
    float x0a = 0.0f, x0b = 0.0f;
    #pragma unroll 4
    for (int k = 0; k < 128; k += 2) {
        const int i0 = ii + k * 8, i1 = ii + (k + 1) * 8;
        x0a = fmaf(e_s[i0], xb[(size_t)i0 * DD], x0a);
        x0b = fmaf(e_s[i1], xb[(size_t)i1 * DD], x0b);
    }
    part[ii][dd] = x0a + x0b;
    __syncthreads();

    if (tid < 32) {
        float x0 = 0.0f;
        #pragma unroll
        for (int p = 0; p < 8; ++p) x0 += part[p][tid];
        x0 /= S;
        const float alpha = alphas[b];
        const float sa  = sqrtf(alpha);
        const float var = 1.0f - alpha;
        const int dout  = dq * 32 + tid;
        out[b * DD + dout] = (inputs[b * DD + dout] - sa * x0) / sqrtf(var);
    }
}

extern "C" void kernel_launch(void* const* d_in, const int* in_sizes, int n_in,
                              void* d_out, int out_size, void* d_ws, size_t ws_size,
                              hipStream_t stream)
{
    const float* inputs = (const float*)d_in[0];   // [B,D]
    const float* alphas = (const float*)d_in[1];   // [B]
    const float* data   = (const float*)d_in[2];   // [N,D]
    float* out = (float*)d_out;
    float* ws  = (float*)d_ws;                     // 16.8 MB x0 + 256 KB ms

    bayes_k1<<<NB, 256, 0, stream>>>(inputs, alphas, data, ws);
    bayes_k2<<<BB * 4, 256, 0, stream>>>(inputs, alphas, ws, out);
}

// Round 9
// 78.977 us; speedup vs baseline: 1.1880x; 1.1711x over previous
//
#include <hip/hip_runtime.h>
#include <math.h>

// BayesPredictor: inputs [B,D] f32, alphas [B] f32, data [N,D] f32
#define BB 32
#define DD 128
#define NN 32768

#define NB 256              // k1 blocks (1/CU), 512 threads, 128 rows each
#define T1 512
#define RPB 128
#define TR 32               // rows per tile
#define NP NB               // partials per b
#define WS_MS_OFF ((size_t)BB * NB * DD)   // floats; ms float2 packed after x0

typedef __attribute__((ext_vector_type(8))) short bf16x8;
typedef __attribute__((ext_vector_type(4))) float f32x4;

// ---- LDS arena (bytes); 16B-granule XOR swizzle on all bf16 tiles
#define O_RH0  0            // rows hi bf16 [32][128] pitch 256, swz (r&7)<<4
#define O_RL0  8192
#define O_RT0  16384        // rows^T hi bf16 [128][32] pitch 64, swz (d&3)<<4
#define O_RH1  24576        // double buffer
#define O_RL1  32768
#define O_RT1  40960
#define O_INH  49152        // inputs hi bf16 [32][128] pitch 256, swz (b&7)<<4
#define O_INL  57344
#define O_D1   65536        // L f32 [32 r][32 b] (k-partial merge + logits)
#define O_NRM  69632        // 2 x 32 f32 (per buffer)
#define O_PT   69888        // P^T bf16 [32 b][32 r] pitch 64, swz (b&3)<<4
#define O_SCL  71936        // 32 f32 rescale factors
#define ARENA  72064
#define O_X0   0            // epilogue x0 f32 [32 b][128 d] pitch 512 (overlays buf0)

__device__ __forceinline__ unsigned bf16_rne(float x) {
    unsigned u = __builtin_bit_cast(unsigned, x);
    return (u + 0x7FFFu + ((u >> 16) & 1u)) >> 16;
}
__device__ __forceinline__ float bf16f(unsigned h) {
    return __builtin_bit_cast(float, h << 16);
}
__device__ __forceinline__ unsigned pk2(float a, float b) {
    return bf16_rne(a) | (bf16_rne(b) << 16);
}

// ---------------- kernel 1: 4 row-tiles, online softmax, register x0 accumulator ----------------
__global__ __launch_bounds__(T1) void bayes_k1(
    const float* __restrict__ inputs, const float* __restrict__ alphas,
    const float* __restrict__ data, float* __restrict__ ws)
{
    __shared__ __align__(16) char arena[ARENA];

    const int tid  = threadIdx.x;
    const int lane = tid & 63;
    const int wv   = tid >> 6;       // 0..7
    const int ln   = lane & 15;
    const int g    = lane >> 4;      // 0..3
    const int bid  = blockIdx.x;

    const int kh  = wv >> 2;         // GEMM1 k-half
    const int nt  = (wv >> 1) & 1;   // GEMM1 b-tile
    const int mtw = wv & 1;          // GEMM1 r-tile

    // staging thread roles
    const int rA  = tid >> 4, cA = tid & 15;    // A: row, 8-float chunk
    const int dB  = tid >> 2, rq = tid & 3;     // B: column d, 8-row group

    // ---- inputs -> INH/INL (once)
    {
        const int b = rA, c16 = cA;
        const float4* gp = (const float4*)(inputs + b * DD + c16 * 8);
        const float4 x0 = gp[0], x1 = gp[1];
        const float v[8] = {x0.x, x0.y, x0.z, x0.w, x1.x, x1.y, x1.z, x1.w};
        unsigned hw[4], lw[4];
        #pragma unroll
        for (int j = 0; j < 4; ++j) {
            const float a = v[2*j], bb = v[2*j+1];
            const unsigned ah = bf16_rne(a), bh = bf16_rne(bb);
            hw[j] = ah | (bh << 16);
            lw[j] = pk2(a - bf16f(ah), bb - bf16f(bh));
        }
        const int go = (c16 * 16) ^ ((b & 7) << 4);
        *(uint4*)(arena + O_INH + b * 256 + go) = make_uint4(hw[0], hw[1], hw[2], hw[3]);
        *(uint4*)(arena + O_INL + b * 256 + go) = make_uint4(lw[0], lw[1], lw[2], lw[3]);
    }

    // per-b softmax constants (waves 0,1 use them)
    float c1 = 0.f, c2 = 0.f;
    if (wv < 2) {
        const int b = wv * 16 + ln;
        const float alpha = alphas[b];
        const float var = 1.0f - alpha;
        c1 = sqrtf(alpha) / var;
        c2 = 0.5f * alpha / var;
    }

    // ---- prologue: load + write tile 0 into buf0
    float4 pa0, pa1; float pbv[8];
    {
        const float4* gpA = (const float4*)(data + ((size_t)bid * RPB + rA) * DD + cA * 8);
        pa0 = gpA[0]; pa1 = gpA[1];
        const float* gpB = data + ((size_t)bid * RPB + rq * 8) * DD + dB;
        #pragma unroll
        for (int j = 0; j < 8; ++j) pbv[j] = gpB[(size_t)j * DD];
    }
    #define STAGE_WRITE(RHo, RLo, RTo, nbuf)                                            \
    {                                                                                   \
        const float v[8] = {pa0.x, pa0.y, pa0.z, pa0.w, pa1.x, pa1.y, pa1.z, pa1.w};    \
        float nn = 0.f;                                                                 \
        _Pragma("unroll") for (int i = 0; i < 8; ++i) nn = fmaf(v[i], v[i], nn);        \
        nn += __shfl_xor(nn, 1); nn += __shfl_xor(nn, 2);                               \
        nn += __shfl_xor(nn, 4); nn += __shfl_xor(nn, 8);                               \
        if (cA == 0) *(float*)(arena + O_NRM + (nbuf) * 128 + rA * 4) = nn;             \
        unsigned hw[4], lw[4];                                                          \
        _Pragma("unroll") for (int j = 0; j < 4; ++j) {                                 \
            const float a = v[2*j], bb = v[2*j+1];                                      \
            const unsigned ah = bf16_rne(a), bh = bf16_rne(bb);                         \
            hw[j] = ah | (bh << 16);                                                    \
            lw[j] = pk2(a - bf16f(ah), bb - bf16f(bh));                                 \
        }                                                                               \
        const int go = (cA * 16) ^ ((rA & 7) << 4);                                     \
        *(uint4*)(arena + (RHo) + rA * 256 + go) = make_uint4(hw[0], hw[1], hw[2], hw[3]); \
        *(uint4*)(arena + (RLo) + rA * 256 + go) = make_uint4(lw[0], lw[1], lw[2], lw[3]); \
        unsigned tw[4];                                                                 \
        _Pragma("unroll") for (int j = 0; j < 4; ++j) tw[j] = pk2(pbv[2*j], pbv[2*j+1]); \
        *(uint4*)(arena + (RTo) + dB * 64 + ((rq * 16) ^ ((dB & 3) << 4))) =            \
            make_uint4(tw[0], tw[1], tw[2], tw[3]);                                     \
    }
    STAGE_WRITE(O_RH0, O_RL0, O_RT0, 0)
    __syncthreads();

    float m_run = -INFINITY, s_run = 0.0f;   // softmax crew state
    f32x4 acc2[2];
    #pragma unroll
    for (int n2 = 0; n2 < 2; ++n2)
        #pragma unroll
        for (int i = 0; i < 4; ++i) acc2[n2][i] = 0.0f;

    #pragma unroll
    for (int t = 0; t < 4; ++t) {
        const int RHc = (t & 1) ? O_RH1 : O_RH0;
        const int RLc = (t & 1) ? O_RL1 : O_RL0;
        const int RTc = (t & 1) ? O_RT1 : O_RT0;
        const int RHn = (t & 1) ? O_RH0 : O_RH1;
        const int RLn = (t & 1) ? O_RL0 : O_RL1;
        const int RTn = (t & 1) ? O_RT0 : O_RT1;

        // T14: issue next-tile global loads now; LDS-write after B2
        if (t < 3) {
            const float4* gpA = (const float4*)(data + ((size_t)bid * RPB + (t + 1) * TR + rA) * DD + cA * 8);
            pa0 = gpA[0]; pa1 = gpA[1];
            const float* gpB = data + ((size_t)bid * RPB + (t + 1) * TR + rq * 8) * DD + dB;
            #pragma unroll
            for (int j = 0; j < 8; ++j) pbv[j] = gpB[(size_t)j * DD];
        }

        // ---- GEMM-1: 16x16 tile (mtw,nt), k-half kh, split-bf16 3-term
        f32x4 acc1;
        #pragma unroll
        for (int i = 0; i < 4; ++i) acc1[i] = 0.0f;
        #pragma unroll
        for (int ks = 0; ks < 2; ++ks) {
            const int kbyte = kh * 128 + ks * 64 + g * 16;
            const int b2 = nt * 16 + ln;
            const int r  = mtw * 16 + ln;
            const bf16x8 Bh = *(const bf16x8*)(arena + O_INH + b2 * 256 + (kbyte ^ ((b2 & 7) << 4)));
            const bf16x8 Bl = *(const bf16x8*)(arena + O_INL + b2 * 256 + (kbyte ^ ((b2 & 7) << 4)));
            const bf16x8 Ah = *(const bf16x8*)(arena + RHc + r * 256 + (kbyte ^ ((r & 7) << 4)));
            const bf16x8 Al = *(const bf16x8*)(arena + RLc + r * 256 + (kbyte ^ ((r & 7) << 4)));
            acc1 = __builtin_amdgcn_mfma_f32_16x16x32_bf16(Ah, Bh, acc1, 0, 0, 0);
            acc1 = __builtin_amdgcn_mfma_f32_16x16x32_bf16(Al, Bh, acc1, 0, 0, 0);
            acc1 = __builtin_amdgcn_mfma_f32_16x16x32_bf16(Ah, Bl, acc1, 0, 0, 0);
        }
        if (kh == 1) {
            #pragma unroll
            for (int i = 0; i < 4; ++i)
                *(float*)(arena + O_D1 + (((mtw * 16 + g * 4 + i) * 32) + nt * 16 + ln) * 4) = acc1[i];
        }
        __syncthreads();   // B2

        if (t < 3) STAGE_WRITE(RHn, RLn, RTn, ((t + 1) & 1))

        if (kh == 0) {
            #pragma unroll
            for (int i = 0; i < 4; ++i) {
                float* p = (float*)(arena + O_D1 + (((mtw * 16 + g * 4 + i) * 32) + nt * 16 + ln) * 4);
                *p = *p + acc1[i];
            }
        }
        __syncthreads();   // B3

        // ---- online softmax (waves 0,1): column b over 32 rows
        if (wv < 2) {
            const int b = wv * 16 + ln;
            float lg[8];
            float mx = -1e30f;
            #pragma unroll
            for (int j = 0; j < 8; ++j) {
                const int r = g * 8 + j;
                const float L  = *(const float*)(arena + O_D1 + (r * 32 + b) * 4);
                const float nr = *(const float*)(arena + O_NRM + (t & 1) * 128 + r * 4);
                lg[j] = fmaf(c1, L, -c2 * nr);
                mx = fmaxf(mx, lg[j]);
            }
            mx = fmaxf(mx, __shfl_xor(mx, 16));
            mx = fmaxf(mx, __shfl_xor(mx, 32));
            const float m_new = fmaxf(m_run, mx);
            const float scl_b = __expf(m_run - m_new);   // t=0: exp(-inf)=0
            float e[8];
            float ssl = 0.0f;
            #pragma unroll
            for (int j = 0; j < 8; ++j) { e[j] = __expf(lg[j] - m_new); ssl += e[j]; }
            ssl += __shfl_xor(ssl, 16);
            ssl += __shfl_xor(ssl, 32);
            s_run = s_run * scl_b + ssl;
            m_run = m_new;
            *(uint4*)(arena + O_PT + b * 64 + ((g * 16) ^ ((b & 3) << 4))) =
                make_uint4(pk2(e[0], e[1]), pk2(e[2], e[3]), pk2(e[4], e[5]), pk2(e[6], e[7]));
            if (g == 0) *(float*)(arena + O_SCL + b * 4) = scl_b;
        }
        __syncthreads();   // B4

        // ---- PV accumulate: wave owns d-tile wv; rescale then 2 MFMAs (K=32)
        {
            const float sc0 = *(const float*)(arena + O_SCL + ln * 4);
            const float sc1 = *(const float*)(arena + O_SCL + (16 + ln) * 4);
            #pragma unroll
            for (int i = 0; i < 4; ++i) { acc2[0][i] *= sc0; acc2[1][i] *= sc1; }
            const int didx = wv * 16 + ln;
            const bf16x8 Ar = *(const bf16x8*)(arena + RTc + didx * 64 + ((g * 16) ^ ((didx & 3) << 4)));
            #pragma unroll
            for (int n2 = 0; n2 < 2; ++n2) {
                const int b2 = n2 * 16 + ln;
                const bf16x8 Bp = *(const bf16x8*)(arena + O_PT + b2 * 64 + ((g * 16) ^ ((b2 & 3) << 4)));
                acc2[n2] = __builtin_amdgcn_mfma_f32_16x16x32_bf16(Ar, Bp, acc2[n2], 0, 0, 0);
            }
        }
        __syncthreads();   // B1 of next tile (publishes stage writes)
    }

    // ---- epilogue: x0 -> LDS [b][d] (overlays buf0), ms write, final coalesced store
    #pragma unroll
    for (int n2 = 0; n2 < 2; ++n2) {
        const int b  = n2 * 16 + ln;
        const int d0 = wv * 16 + g * 4;
        *(f32x4*)(arena + O_X0 + b * 512 + ((d0 * 4) ^ ((b & 7) << 4))) = acc2[n2];
    }
    if (wv < 2 && g == 0) {
        const int b = wv * 16 + ln;
        *(float2*)(ws + WS_MS_OFF + ((size_t)b * NB + bid) * 2) = make_float2(m_run, s_run);
    }
    __syncthreads();
    {
        const int b = tid >> 4, c16 = tid & 15;
        const int swzb = (b & 7) << 4;
        const f32x4 v0 = *(const f32x4*)(arena + O_X0 + b * 512 + ((c16 * 32) ^ swzb));
        const f32x4 v1 = *(const f32x4*)(arena + O_X0 + b * 512 + ((c16 * 32 + 16) ^ swzb));
        float* dst = ws + ((size_t)b * NB + bid) * DD + c16 * 8;
        *(f32x4*)dst = v0;
        *(f32x4*)(dst + 4) = v1;
    }
}

// ---------------- kernel 2: cross-block softmax combine + output ----------------
__global__ __launch_bounds__(256) void bayes_k2(
    const float* __restrict__ inputs, const float* __restrict__ alphas,
    const float* __restrict__ ws, float* __restrict__ out)
{
    const int b   = blockIdx.x >> 2;   // 0..31
    const int dq  = blockIdx.x & 3;    // d-quarter
    const int tid = threadIdx.x;

    __shared__ float e_s[NP];
    __shared__ float red_s[16];
    __shared__ float part[8][32];

    // packed m,s: 256 float2, contiguous per b (2 KB)
    const float2 v = *(const float2*)(ws + WS_MS_OFF + ((size_t)b * NP + tid) * 2);
    const float mi = v.x, si = v.y;

    float mm = mi;
    #pragma unroll
    for (int off = 1; off <= 32; off <<= 1) mm = fmaxf(mm, __shfl_xor(mm, off));
    if ((tid & 63) == 0) red_s[tid >> 6] = mm;
    __syncthreads();
    const float M = fmaxf(fmaxf(red_s[0], red_s[1]), fmaxf(red_s[2], red_s[3]));

    const float ei = __expf(mi - M);
    e_s[tid] = ei;
    float ss = si * ei;
    #pragma unroll
    for (int off = 1; off <= 32; off <<= 1) ss += __shfl_xor(ss, off);
    if ((tid & 63) == 0) red_s[8 + (tid >> 6)] = ss;
    __syncthreads();
    const float S = (red_s[8] + red_s[9]) + (red_s[10] + red_s[11]);

    // gather: 32 d-values, 8-way split over 256 partials (32 each), coalesced 128-B rows
    const int dd = tid & 31, ii = tid >> 5;
    const int d  = dq * 32 + dd;
    const float* xb = ws + (size_t)b * NP * DD + d;
    float x0a = 0.0f, x0b = 0.0f;
    #pragma unroll 4
    for (int k = 0; k < 32; k += 2) {
        const int i0 = ii + k * 8, i1 = ii + (k + 1) * 8;
        x0a = fmaf(e_s[i0], xb[(size_t)i0 * DD], x0a);
        x0b = fmaf(e_s[i1], xb[(size_t)i1 * DD], x0b);
    }
    part[ii][dd] = x0a + x0b;
    __syncthreads();

    if (tid < 32) {
        float x0 = 0.0f;
        #pragma unroll
        for (int p = 0; p < 8; ++p) x0 += part[p][tid];
        x0 /= S;
        const float alpha = alphas[b];
        const float sa  = sqrtf(alpha);
        const float var = 1.0f - alpha;
        const int dout  = dq * 32 + tid;
        out[b * DD + dout] = (inputs[b * DD + dout] - sa * x0) / sqrtf(var);
    }
}

extern "C" void kernel_launch(void* const* d_in, const int* in_sizes, int n_in,
                              void* d_out, int out_size, void* d_ws, size_t ws_size,
                              hipStream_t stream)
{
    const float* inputs = (const float*)d_in[0];   // [B,D]
    const float* alphas = (const float*)d_in[1];   // [B]
    const float* data   = (const float*)d_in[2];   // [N,D]
    float* out = (float*)d_out;
    float* ws  = (float*)d_ws;                     // 4 MB x0 + 64 KB ms

    bayes_k1<<<NB, T1, 0, stream>>>(inputs, alphas, data, ws);
    bayes_k2<<<BB * 4, 256, 0, stream>>>(inputs, alphas, ws, out);
}